// Round 10
// baseline (139.966 us; speedup 1.0000x reference)
//
#include <hip/hip_runtime.h>

// NT-Xent loss, fused: never materialize the 8192x8192 similarity matrix.
// z = concat(z1,z2) [8192,256] f32 -> normalize -> fp8 e4m3 zn8 (ws)
// S = zn8 @ zn8^T via mfma_f32_16x16x32_fp8_fp8, fused per-row sum of
// exp(2*cos - 2) (fixed logsumexp max = 2: logits bounded -> partials additive)
// nll_r = -pos_r + 2 + log(sum_r); out = mean(nll)
//
// R10: fp8 operands break the rows/wave <-> VGPR <-> occupancy squeeze:
// 64 rows/wave costs 64 VGPR of A (4 waves/SIMD), B via ds_read_b64 puts the
// LDS port off the critical path (R6 audit: LDS 27us/CU > MFMA 16.5us floor).
// fp8 MFMA = bf16 rate; cos abs err ~3e-3 << 0.18 threshold.
// Grid 32x32 = 1024 blocks = exactly 4/CU; LDS 2x16KB dbuf; 16B-slot XOR
// swizzle slot^=(col&15) on BOTH stage source and ds_read (rule #21).

#define NHALF 4096
#define N2 8192
#define D 256
#define CSPLIT 32
#define NPH 4       // phases per chunk; 64 cols per phase
#define RPB 256     // rows per block (4 waves x 64)

typedef __attribute__((ext_vector_type(4))) float f32x4;

__device__ __forceinline__ unsigned char f2fp8(float f) {
  // OCP e4m3fn, RNE; inputs |f| <= 1 (normalized rows): no sat/NaN path.
  unsigned int u = __float_as_uint(f);
  unsigned char s = (unsigned char)((u >> 24) & 0x80u);
  int e = (int)((u >> 23) & 0xffu) - 127;
  unsigned int m = u & 0x7fffffu;
  if (e >= -6) {  // normal fp8 range
    unsigned int r = m + 0x7ffffu + ((m >> 20) & 1u);  // RNE at bit 20
    if (r >= 0x800000u) { r = 0; ++e; } else r >>= 20;
    return (unsigned char)(s | (unsigned int)((e + 7) << 3) | r);
  }
  // subnormal/zero: quantize to step 2^-9 (exp field 0)
  int q = (int)rintf(fabsf(f) * 512.0f);
  return (unsigned char)(s | (unsigned int)q);
}

__device__ __forceinline__ void gload_lds16(const void* g, void* l) {
  __builtin_amdgcn_global_load_lds(
      (const __attribute__((address_space(1))) unsigned int*)g,
      (__attribute__((address_space(3))) unsigned int*)l, 16, 0, 0);
}

// ---------------- Kernel 1: row-normalize to fp8 ----------------
__global__ __launch_bounds__(256) void norm_kernel(const float* __restrict__ z1,
                                                   const float* __restrict__ z2,
                                                   unsigned char* __restrict__ zn8) {
  const int lane = threadIdx.x & 63;
  const int row = blockIdx.x * 4 + (threadIdx.x >> 6);
  const float* src = (row < NHALF) ? (z1 + (size_t)row * D)
                                   : (z2 + (size_t)(row - NHALF) * D);
  const float4 v = *(const float4*)(src + lane * 4);
  float ss = v.x * v.x + v.y * v.y + v.z * v.z + v.w * v.w;
  #pragma unroll
  for (int m = 1; m < 64; m <<= 1) ss += __shfl_xor(ss, m);
  const float inv = 1.0f / fmaxf(sqrtf(ss), 1e-8f);
  unsigned int o = (unsigned int)f2fp8(v.x * inv) |
                   ((unsigned int)f2fp8(v.y * inv) << 8) |
                   ((unsigned int)f2fp8(v.z * inv) << 16) |
                   ((unsigned int)f2fp8(v.w * inv) << 24);
  *(unsigned int*)(zn8 + (size_t)row * D + lane * 4) = o;
}

// ---------------- Kernel 2: fused Gram + partial exp-sums ----------------
// grid (32 row-blocks, 32 col-chunks), 256 threads = 4 waves.
// Wave owns 64 rows = 4 stripes of 16; A in regs (64 VGPR); B in LDS.
// mfma_f32_16x16x32_fp8_fp8: A/B lane l -> row/col (l&15), k = 8*(l>>4)+e
//   (8 contiguous bytes); D lane l -> col (l&15), row = 4*(l>>4)+g.
// LDS B: [64 cols][256 B], 16B slots swizzled slot^=(col&15); dbuf 2x16KB.
__global__ __launch_bounds__(256, 4) void simlse_kernel(const unsigned char* __restrict__ zn8,
                                                        float* __restrict__ sum_ws,
                                                        float* __restrict__ pos_ws) {
  __shared__ __align__(16) char bsm[32768];
  const int lane = threadIdx.x & 63;
  const int wave = threadIdx.x >> 6;
  const int r16 = lane & 15;
  const int h = lane >> 4;  // 0..3
  const int rowbase = blockIdx.x * RPB + wave * 64;
  const int cc = blockIdx.y;

  // A fragments: 4 stripes x 8 K-steps, 8B contiguous per lane (64 VGPR).
  long a[4][8];
  #pragma unroll
  for (int st = 0; st < 4; ++st) {
    const unsigned char* ap = zn8 + (size_t)(rowbase + st * 16 + r16) * D + h * 8;
    #pragma unroll
    for (int s = 0; s < 8; ++s) a[st][s] = *(const long*)(ap + s * 32);
  }
  #pragma unroll
  for (int st = 0; st < 4; ++st)
    #pragma unroll
    for (int s = 0; s < 8; ++s) asm volatile("" : "+v"(a[st][s]));

  float lsum[4][4];
  #pragma unroll
  for (int st = 0; st < 4; ++st)
    #pragma unroll
    for (int g = 0; g < 4; ++g) lsum[st][g] = 0.0f;

  int dt[4], pt[4];
  #pragma unroll
  for (int st = 0; st < 4; ++st) {
    dt[st] = (rowbase + st * 16) >> 4;                      // diagonal tile
    pt[st] = ((rowbase + st * 16 + NHALF) & (N2 - 1)) >> 4; // positive tile
  }

  // Stage 64 cols (16 KB) into LDS buffer. Linear y: col = y>>8,
  // slot16 = (y>>4)&15; source slot = slot16 ^ (col&15) (involution).
  auto stage = [&](int buf, int ph) {
    const int colbase = cc * 256 + ph * 64;
    #pragma unroll
    for (int s = 0; s < 4; ++s) {
      const int y = wave * 4096 + s * 1024 + lane * 16;
      const int col = y >> 8;
      const int slot = ((y >> 4) & 15) ^ (col & 15);
      const void* gp = zn8 + (size_t)(colbase + col) * D + slot * 16;
      void* lp = bsm + buf * 16384 + wave * 4096 + s * 1024;  // +lane*16 by HW
      gload_lds16(gp, lp);
    }
  };

  stage(0, 0);
  __syncthreads();
  for (int ph = 0; ph < NPH; ++ph) {
    if (ph + 1 < NPH) stage((ph + 1) & 1, ph + 1);  // DMA overlaps compute
    const char* base = bsm + (ph & 1) * 16384;
    #pragma unroll
    for (int j = 0; j < 4; ++j) {
      const int ct = cc * 16 + ph * 4 + j;
      f32x4 acc[4];
      #pragma unroll
      for (int st = 0; st < 4; ++st) acc[st] = (f32x4){0.f, 0.f, 0.f, 0.f};
      #pragma unroll
      for (int s = 0; s < 8; ++s) {
        const int slot16 = (s * 2 + (h >> 1)) ^ r16;  // swizzled 16B slot
        const long b = *(const long*)(base + (j * 16 + r16) * 256 +
                                      slot16 * 16 + (h & 1) * 8);
        #pragma unroll
        for (int st = 0; st < 4; ++st)
          acc[st] = __builtin_amdgcn_mfma_f32_16x16x32_fp8_fp8(a[st][s], b, acc[st], 0, 0, 0);
      }
      #pragma unroll
      for (int st = 0; st < 4; ++st) {
        const bool isd = (ct == dt[st]);
        const bool isp = (ct == pt[st]);
        if (!isd && !isp) {
          #pragma unroll
          for (int g = 0; g < 4; ++g)
            lsum[st][g] += __expf(fmaf(acc[st][g], 2.0f, -2.0f));
        } else {
          #pragma unroll
          for (int g = 0; g < 4; ++g) {
            const int rl = (h << 2) + g;    // local row 0..15
            const bool hit = (r16 == rl);   // tile-diagonal element
            float e = __expf(fmaf(acc[st][g], 2.0f, -2.0f));
            if (isd && hit) e = 0.0f;       // mask self-similarity
            if (isp && hit) pos_ws[rowbase + st * 16 + rl] = acc[st][g] * 2.0f;
            lsum[st][g] += e;
          }
        }
      }
    }
    __syncthreads();
  }

  // Reduce exp-sums across each 16-lane column group.
  #pragma unroll
  for (int st = 0; st < 4; ++st)
    #pragma unroll
    for (int g = 0; g < 4; ++g) {
      #pragma unroll
      for (int m = 1; m < 16; m <<= 1)
        lsum[st][g] += __shfl_xor(lsum[st][g], m);
    }
  if (r16 == 0) {
    #pragma unroll
    for (int st = 0; st < 4; ++st)
      #pragma unroll
      for (int g = 0; g < 4; ++g) {
        const int r = rowbase + st * 16 + (h << 2) + g;
        sum_ws[(size_t)r * CSPLIT + cc] = lsum[st][g];
      }
  }
}

// ---------------- Kernel 3a: per-row nll + per-block partial sum ----------------
__global__ __launch_bounds__(256) void nll_kernel(const float* __restrict__ sum_ws,
                                                  const float* __restrict__ pos_ws,
                                                  float* __restrict__ partial) {
  const int r = blockIdx.x * 256 + threadIdx.x;
  const float4* sp = (const float4*)(sum_ws + (size_t)r * CSPLIT);
  float t = 0.0f;
  #pragma unroll
  for (int i = 0; i < CSPLIT / 4; ++i) {
    const float4 v = sp[i];
    t += v.x + v.y + v.z + v.w;
  }
  float nll = -pos_ws[r] + 2.0f + __logf(t);
  #pragma unroll
  for (int m = 1; m < 64; m <<= 1) nll += __shfl_xor(nll, m);
  __shared__ float red[4];
  const int lane = threadIdx.x & 63;
  const int wave = threadIdx.x >> 6;
  if (lane == 0) red[wave] = nll;
  __syncthreads();
  if (threadIdx.x == 0) partial[blockIdx.x] = red[0] + red[1] + red[2] + red[3];
}

// ---------------- Kernel 3b: final mean ----------------
__global__ __launch_bounds__(64) void final_kernel(const float* __restrict__ partial,
                                                   float* __restrict__ out) {
  const int lane = threadIdx.x;
  float v = (lane < 32) ? partial[lane] : 0.0f;
  #pragma unroll
  for (int m = 1; m < 64; m <<= 1) v += __shfl_xor(v, m);
  if (lane == 0) out[0] = v * (1.0f / (float)N2);
}

extern "C" void kernel_launch(void* const* d_in, const int* in_sizes, int n_in,
                              void* d_out, int out_size, void* d_ws, size_t ws_size,
                              hipStream_t stream) {
  const float* z1 = (const float*)d_in[0];
  const float* z2 = (const float*)d_in[1];
  float* out = (float*)d_out;

  char* ws = (char*)d_ws;
  unsigned char* zn8 = (unsigned char*)ws;                  // 8192*256 = 2 MB
  float* sum_ws = (float*)(ws + (size_t)N2 * D);            // 8192*32*4 = 1 MB
  float* pos_ws = sum_ws + (size_t)N2 * CSPLIT;             // 8192*4 = 32 KB
  float* partial = pos_ws + N2;                             // 32 floats

  hipLaunchKernelGGL(norm_kernel, dim3(N2 / 4), dim3(256), 0, stream, z1, z2, zn8);
  hipLaunchKernelGGL(simlse_kernel, dim3(N2 / RPB, CSPLIT), dim3(256), 0, stream,
                     zn8, sum_ws, pos_ws);
  hipLaunchKernelGGL(nll_kernel, dim3(N2 / 256), dim3(256), 0, stream, sum_ws, pos_ws, partial);
  hipLaunchKernelGGL(final_kernel, dim3(1), dim3(64), 0, stream, partial, out);
}

// Round 11
// 47.662 us; speedup vs baseline: 2.9367x; 2.9367x over previous
//
#include <hip/hip_runtime.h>

// NT-Xent loss, fused: never materialize the 8192x8192 similarity matrix.
// z = concat(z1,z2) [8192,256] f32 -> normalize -> fp8 e4m3 zn8 (ws)
// S = zn8 @ zn8^T via mfma_f32_16x16x32_fp8_fp8, fused per-row sum of
// exp(2*cos - 2) (fixed logsumexp max = 2: logits bounded -> partials additive)
// nll_r = -pos_r + 2 + log(sum_r); out = mean(nll)
//
// R11 = R6's verified skeleton (45.7us; 128 rows/block, 2 tiles/phase, 16
// phases, 2-barrier loop, 4 blocks/CU) with fp8 operands. Halves every LDS
// byte at the SAME MFMA count (fp8 16x16x32 = bf16 shape/rate): B becomes
// ds_read_b64 (~10us/CU, off critical path vs 16.5us MFMA floor), A = 32
// VGPR (no spill; R8/R9/R10 all died spilling >=64-VGPR pinned A arrays).
// fp8 numerics + fragment layout verified correct by R10's pass.
// Conflict-free b64 swizzle: inner ^= (col&3)<<5 on stage source AND read.

#define NHALF 4096
#define N2 8192
#define D 256
#define CSPLIT 16
#define NPH 16      // phases per chunk; 2 tiles (32 cols) per phase
#define RPB 128     // rows per block (4 waves x 32)

typedef __attribute__((ext_vector_type(4))) float f32x4;

__device__ __forceinline__ unsigned char f2fp8(float f) {
  // OCP e4m3fn, RNE; inputs |f| <= 1 (normalized rows): no sat/NaN path.
  unsigned int u = __float_as_uint(f);
  unsigned char s = (unsigned char)((u >> 24) & 0x80u);
  int e = (int)((u >> 23) & 0xffu) - 127;
  unsigned int m = u & 0x7fffffu;
  if (e >= -6) {  // normal fp8 range
    unsigned int r = m + 0x7ffffu + ((m >> 20) & 1u);  // RNE at bit 20
    if (r >= 0x800000u) { r = 0; ++e; } else r >>= 20;
    return (unsigned char)(s | (unsigned int)((e + 7) << 3) | r);
  }
  // subnormal/zero: quantize to step 2^-9 (exp field 0)
  int q = (int)rintf(fabsf(f) * 512.0f);
  return (unsigned char)(s | (unsigned int)q);
}

__device__ __forceinline__ void gload_lds16(const void* g, void* l) {
  __builtin_amdgcn_global_load_lds(
      (const __attribute__((address_space(1))) unsigned int*)g,
      (__attribute__((address_space(3))) unsigned int*)l, 16, 0, 0);
}

// ---------------- Kernel 1: row-normalize to fp8 ----------------
__global__ __launch_bounds__(256) void norm_kernel(const float* __restrict__ z1,
                                                   const float* __restrict__ z2,
                                                   unsigned char* __restrict__ zn8) {
  const int lane = threadIdx.x & 63;
  const int row = blockIdx.x * 4 + (threadIdx.x >> 6);
  const float* src = (row < NHALF) ? (z1 + (size_t)row * D)
                                   : (z2 + (size_t)(row - NHALF) * D);
  const float4 v = *(const float4*)(src + lane * 4);
  float ss = v.x * v.x + v.y * v.y + v.z * v.z + v.w * v.w;
  #pragma unroll
  for (int m = 1; m < 64; m <<= 1) ss += __shfl_xor(ss, m);
  const float inv = 1.0f / fmaxf(sqrtf(ss), 1e-8f);
  unsigned int o = (unsigned int)f2fp8(v.x * inv) |
                   ((unsigned int)f2fp8(v.y * inv) << 8) |
                   ((unsigned int)f2fp8(v.z * inv) << 16) |
                   ((unsigned int)f2fp8(v.w * inv) << 24);
  *(unsigned int*)(zn8 + (size_t)row * D + lane * 4) = o;
}

// ---------------- Kernel 2: fused Gram + partial exp-sums ----------------
// grid (64 row-blocks, 16 col-chunks), 256 threads = 4 waves.
// Wave owns 32 rows = 2 stripes of 16; A in regs (32 VGPR); B in LDS.
// mfma_f32_16x16x32_fp8_fp8: A/B lane l -> row/col (l&15), k-bytes
//   8*(l>>4)..+7 (verified by R10 pass); D lane l -> col (l&15), row 4*(l>>4)+g.
// LDS B: 2 buffers x [2 tiles][16 cols][256 B]; swizzle inner ^= (col&3)<<5
// (banks (kk*8+2h)^8*(col&3): 4 lanes/bank-pair = 4-cycle floor, conflict-free)
// applied to BOTH the stage source and the ds_read (rule #21).
__global__ __launch_bounds__(256, 4) void simlse_kernel(const unsigned char* __restrict__ zn8,
                                                        float* __restrict__ sum_ws,
                                                        float* __restrict__ pos_ws) {
  __shared__ __align__(16) char bsm[16384];  // 2 x 8 KB
  const int lane = threadIdx.x & 63;
  const int wave = threadIdx.x >> 6;
  const int r16 = lane & 15;
  const int h = lane >> 4;  // 0..3
  const int rowbase = blockIdx.x * RPB + wave * 32;
  const int cc = blockIdx.y;

  // A fragments: 2 stripes x 8 K-steps, 8B contiguous per lane (32 VGPR).
  long a[2][8];
  #pragma unroll
  for (int st = 0; st < 2; ++st) {
    const unsigned char* ap = zn8 + (size_t)(rowbase + st * 16 + r16) * D + h * 8;
    #pragma unroll
    for (int s = 0; s < 8; ++s) a[st][s] = *(const long*)(ap + s * 32);
  }
  #pragma unroll
  for (int st = 0; st < 2; ++st)
    #pragma unroll
    for (int s = 0; s < 8; ++s) asm volatile("" : "+v"(a[st][s]));

  float lsum[2][4];
  #pragma unroll
  for (int st = 0; st < 2; ++st)
    #pragma unroll
    for (int g = 0; g < 4; ++g) lsum[st][g] = 0.0f;

  int dt[2], pt[2];
  #pragma unroll
  for (int st = 0; st < 2; ++st) {
    dt[st] = (rowbase + st * 16) >> 4;                      // diagonal tile
    pt[st] = ((rowbase + st * 16 + NHALF) & (N2 - 1)) >> 4; // positive tile
  }

  // Stage 2 tiles (8 KB) into LDS buffer. Linear y in [0,8192):
  // tile = y>>12, col = (y>>8)&15, inner = y&255; src inner ^= (col&3)<<5
  // (involution, 16B-aligned: XOR touches bits 5-6 only).
  auto stage = [&](int buf, int ph) {
    const int colbase = cc * 512 + ph * 32;
    #pragma unroll
    for (int s = 0; s < 2; ++s) {
      const int y = s * 4096 + wave * 1024 + lane * 16;
      const int col = (y >> 8) & 15;
      const int inner = (y & 255) ^ ((col & 3) << 5);
      const void* gp = zn8 + (size_t)(colbase + (y >> 12) * 16 + col) * D + inner;
      void* lp = bsm + buf * 8192 + s * 4096 + wave * 1024;  // +lane*16 by HW
      gload_lds16(gp, lp);
    }
  };

  stage(0, 0);
  __syncthreads();
  for (int ph = 0; ph < NPH; ++ph) {
    if (ph + 1 < NPH) stage((ph + 1) & 1, ph + 1);  // DMA overlaps compute
    const char* base = bsm + (ph & 1) * 8192;
    #pragma unroll
    for (int j = 0; j < 2; ++j) {
      const int ct = cc * 32 + ph * 2 + j;
      const char* tb = base + j * 4096 + r16 * 256;
      const int sw = (r16 & 3) << 5;
      f32x4 acc[2];
      acc[0] = (f32x4){0.f, 0.f, 0.f, 0.f};
      acc[1] = (f32x4){0.f, 0.f, 0.f, 0.f};
      #pragma unroll
      for (int s = 0; s < 8; ++s) {
        const long b = *(const long*)(tb + ((s * 32 + h * 8) ^ sw));
        acc[0] = __builtin_amdgcn_mfma_f32_16x16x32_fp8_fp8(a[0][s], b, acc[0], 0, 0, 0);
        acc[1] = __builtin_amdgcn_mfma_f32_16x16x32_fp8_fp8(a[1][s], b, acc[1], 0, 0, 0);
      }
      #pragma unroll
      for (int st = 0; st < 2; ++st) {
        const bool isd = (ct == dt[st]);
        const bool isp = (ct == pt[st]);
        if (!isd && !isp) {
          #pragma unroll
          for (int g = 0; g < 4; ++g)
            lsum[st][g] += __expf(fmaf(acc[st][g], 2.0f, -2.0f));
        } else {
          #pragma unroll
          for (int g = 0; g < 4; ++g) {
            const int rl = (h << 2) + g;    // local row 0..15
            const bool hit = (r16 == rl);   // tile-diagonal element
            float e = __expf(fmaf(acc[st][g], 2.0f, -2.0f));
            if (isd && hit) e = 0.0f;       // mask self-similarity
            if (isp && hit) pos_ws[rowbase + st * 16 + rl] = acc[st][g] * 2.0f;
            lsum[st][g] += e;
          }
        }
      }
    }
    __syncthreads();
  }

  // Reduce exp-sums across each 16-lane column group.
  #pragma unroll
  for (int st = 0; st < 2; ++st)
    #pragma unroll
    for (int g = 0; g < 4; ++g) {
      #pragma unroll
      for (int m = 1; m < 16; m <<= 1)
        lsum[st][g] += __shfl_xor(lsum[st][g], m);
    }
  if (r16 == 0) {
    #pragma unroll
    for (int st = 0; st < 2; ++st)
      #pragma unroll
      for (int g = 0; g < 4; ++g) {
        const int r = rowbase + st * 16 + (h << 2) + g;
        sum_ws[(size_t)r * CSPLIT + cc] = lsum[st][g];
      }
  }
}

// ---------------- Kernel 3a: per-row nll + per-block partial sum ----------------
__global__ __launch_bounds__(256) void nll_kernel(const float* __restrict__ sum_ws,
                                                  const float* __restrict__ pos_ws,
                                                  float* __restrict__ partial) {
  const int r = blockIdx.x * 256 + threadIdx.x;
  const float4* sp = (const float4*)(sum_ws + (size_t)r * CSPLIT);
  float t = 0.0f;
  #pragma unroll
  for (int i = 0; i < CSPLIT / 4; ++i) {
    const float4 v = sp[i];
    t += v.x + v.y + v.z + v.w;
  }
  float nll = -pos_ws[r] + 2.0f + __logf(t);
  #pragma unroll
  for (int m = 1; m < 64; m <<= 1) nll += __shfl_xor(nll, m);
  __shared__ float red[4];
  const int lane = threadIdx.x & 63;
  const int wave = threadIdx.x >> 6;
  if (lane == 0) red[wave] = nll;
  __syncthreads();
  if (threadIdx.x == 0) partial[blockIdx.x] = red[0] + red[1] + red[2] + red[3];
}

// ---------------- Kernel 3b: final mean ----------------
__global__ __launch_bounds__(64) void final_kernel(const float* __restrict__ partial,
                                                   float* __restrict__ out) {
  const int lane = threadIdx.x;
  float v = (lane < 32) ? partial[lane] : 0.0f;
  #pragma unroll
  for (int m = 1; m < 64; m <<= 1) v += __shfl_xor(v, m);
  if (lane == 0) out[0] = v * (1.0f / (float)N2);
}

extern "C" void kernel_launch(void* const* d_in, const int* in_sizes, int n_in,
                              void* d_out, int out_size, void* d_ws, size_t ws_size,
                              hipStream_t stream) {
  const float* z1 = (const float*)d_in[0];
  const float* z2 = (const float*)d_in[1];
  float* out = (float*)d_out;

  char* ws = (char*)d_ws;
  unsigned char* zn8 = (unsigned char*)ws;                  // 8192*256 = 2 MB
  float* sum_ws = (float*)(ws + (size_t)N2 * D);            // 8192*16*4 = 512 KB
  float* pos_ws = sum_ws + (size_t)N2 * CSPLIT;             // 8192*4 = 32 KB
  float* partial = pos_ws + N2;                             // 32 floats

  hipLaunchKernelGGL(norm_kernel, dim3(N2 / 4), dim3(256), 0, stream, z1, z2, zn8);
  hipLaunchKernelGGL(simlse_kernel, dim3(N2 / RPB, CSPLIT), dim3(256), 0, stream,
                     zn8, sum_ws, pos_ws);
  hipLaunchKernelGGL(nll_kernel, dim3(N2 / 256), dim3(256), 0, stream, sum_ws, pos_ws, partial);
  hipLaunchKernelGGL(final_kernel, dim3(1), dim3(64), 0, stream, partial, out);
}